// Round 10
// baseline (48.575 us; speedup 1.0000x reference)
//
#include <hip/hip_runtime.h>
#include <hip/hip_bf16.h>

#define NS 32
#define FD 512
#define K_INST 256
#define CHUNK 256            // floats of FD staged per pass
#define C4 (CHUNK/4)         // 64 float4 per row-chunk
#define PADF 260             // staged row stride in floats
#define PAD4 (PADF/4)        // 65
#define MPAD 33              // 32x32 matrix padded to 33 cols
#define HSIC_BLOCKS 512      // one RBF matrix per block: k = bid>>1, m = bid&1
#define GATE_BLOCKS 1024
#define GATE_ITERS 32        // 8388608 float4 / (1024*256) exactly

__device__ __forceinline__ float wave_reduce_add(float v) {
  for (int off = 32; off; off >>= 1) v += __shfl_down(v, off, 64);
  return v;
}

// ---- k1: gather + Gram + dist (hsic blocks) fused with gate stream ----
__global__ __launch_bounds__(256) void fused_kernel(
    const float* __restrict__ dp, const float* __restrict__ gate,
    const int* __restrict__ inst_idx, const int* __restrict__ bg_idx,
    float* __restrict__ ws_gate, float* __restrict__ ws_dist) {

  __shared__ float sX[NS * PADF];        // 33280 B staging
  __shared__ float sN2[NS];
  __shared__ int   sIdx[NS];
  __shared__ float sWaveRed[4];

  const int tid  = threadIdx.x;
  const int bid  = blockIdx.x;
  const int lane = tid & 63;
  const int w    = tid >> 6;

  if (bid >= HSIC_BLOCKS) {
    // ---- gate |x| partial sum: exactly 32 float4 per thread, no tail ----
    const int gb = bid - HSIC_BLOCKS;
    const float4* g4 = reinterpret_cast<const float4*>(gate);
    float s = 0.f;
    size_t base = (size_t)gb * 256 + tid;
    #pragma unroll 8
    for (int it = 0; it < GATE_ITERS; ++it) {
      float4 v = g4[base + (size_t)it * (GATE_BLOCKS * 256)];
      s += fabsf(v.x) + fabsf(v.y) + fabsf(v.z) + fabsf(v.w);
    }
    s = wave_reduce_add(s);
    if (lane == 0) sWaveRed[w] = s;
    __syncthreads();
    if (tid == 0) ws_gate[gb] = sWaveRed[0] + sWaveRed[1] + sWaveRed[2] + sWaveRed[3];
    return;
  }

  // ---- one dist matrix: instance k, side m ----
  const int k  = bid >> 1;
  const int m  = bid & 1;
  const int ti = tid >> 4;   // 0..15
  const int tj = tid & 15;   // 0..15
  const float4* sX4 = reinterpret_cast<const float4*>(sX);

  const int* idx = (m == 0 ? inst_idx : bg_idx) + k * NS;
  if (tid < NS) sIdx[tid] = idx[tid];
  __syncthreads();

  // raw Gram, strided 2x2 tile per thread: rows {ti,ti+16} x cols {tj,tj+16}
  float a00 = 0.f, a01 = 0.f, a10 = 0.f, a11 = 0.f;
  for (int ch = 0; ch < 2; ++ch) {
    for (int q = tid; q < NS * C4; q += 256) {
      int r = q >> 6, c = q & 63;
      float4 v = *(reinterpret_cast<const float4*>(dp + (size_t)sIdx[r] * FD + ch * CHUNK) + c);
      *(reinterpret_cast<float4*>(&sX[r * PADF]) + c) = v;
    }
    __syncthreads();
    #pragma unroll 4
    for (int c = 0; c < C4; ++c) {
      float4 x0 = sX4[ti * PAD4 + c];
      float4 x1 = sX4[(ti + 16) * PAD4 + c];
      float4 y0 = sX4[tj * PAD4 + c];
      float4 y1 = sX4[(tj + 16) * PAD4 + c];
      a00 += x0.x*y0.x + x0.y*y0.y + x0.z*y0.z + x0.w*y0.w;
      a01 += x0.x*y1.x + x0.y*y1.y + x0.z*y1.z + x0.w*y1.w;
      a10 += x1.x*y0.x + x1.y*y0.y + x1.z*y0.z + x1.w*y0.w;
      a11 += x1.x*y1.x + x1.y*y1.y + x1.z*y1.z + x1.w*y1.w;
    }
    __syncthreads();
  }

  // norms from Gram diagonal
  if (ti == tj) { sN2[ti] = a00; sN2[ti + 16] = a11; }
  __syncthreads();
  float i0 = 1.f / fmaxf(sqrtf(sN2[ti]),      1e-12f);
  float i1 = 1.f / fmaxf(sqrtf(sN2[ti + 16]), 1e-12f);
  float j0 = 1.f / fmaxf(sqrtf(sN2[tj]),      1e-12f);
  float j1 = 1.f / fmaxf(sqrtf(sN2[tj + 16]), 1e-12f);

  // dist = max(2 - 2*Gn, 0), exact 0 diagonal -> workspace
  float d0 = (ti == tj) ? 0.f : fmaxf(2.f - 2.f * a00 * i0 * j0, 0.f);
  float d1 = fmaxf(2.f - 2.f * a01 * i0 * j1, 0.f);
  float d2 = fmaxf(2.f - 2.f * a10 * i1 * j0, 0.f);
  float d3 = (ti == tj) ? 0.f : fmaxf(2.f - 2.f * a11 * i1 * j1, 0.f);

  float* dst = ws_dist + (size_t)bid * 1024;
  dst[ti * 32 + tj]               = d0;
  dst[ti * 32 + tj + 16]          = d1;
  dst[(ti + 16) * 32 + tj]        = d2;
  dst[(ti + 16) * 32 + tj + 16]   = d3;
}

// ---- k2: dual radix-median + exp + row means + contraction, one block per instance ----
__global__ __launch_bounds__(256) void contract_kernel(
    const float* __restrict__ ws_dist, float* __restrict__ ws_hs) {
  __shared__ float sK[NS * MPAD];
  __shared__ float sL[NS * MPAD];
  __shared__ float sRM[2][NS];
  __shared__ float sWaveRed[4];
  __shared__ int   sHist[256];
  __shared__ int   sWaveSum[4];
  __shared__ unsigned sPrefix;
  __shared__ int   sWant;
  __shared__ float sSig[2];

  const int k = blockIdx.x;
  const int tid = threadIdx.x, lane = tid & 63, w = tid >> 6;

  const float4* dK4 = reinterpret_cast<const float4*>(ws_dist + (size_t)(2 * k) * 1024);
  const float4* dL4 = reinterpret_cast<const float4*>(ws_dist + (size_t)(2 * k + 1) * 1024);
  float4 vK = dK4[tid];
  float4 vL = dL4[tid];

  sHist[tid] = 0;
  if (tid == 0) { sPrefix = 0u; sWant = (NS * NS - 1) / 2; }
  __syncthreads();

  // exact lower-median via 4-pass MSD radix select, for K then L
  for (int mm = 0; mm < 2; ++mm) {
    float4 v = mm ? vL : vK;
    unsigned u[4] = { __float_as_uint(v.x), __float_as_uint(v.y),
                      __float_as_uint(v.z), __float_as_uint(v.w) };
    for (int shift = 24; shift >= 0; shift -= 8) {
      unsigned pref = sPrefix;
      int want = sWant;
      unsigned hi_mask = (shift == 24) ? 0u : (0xFFFFFFFFu << (shift + 8));
      #pragma unroll
      for (int s = 0; s < 4; ++s)
        if ((u[s] & hi_mask) == pref) atomicAdd(&sHist[(u[s] >> shift) & 255], 1);
      __syncthreads();
      int vv = sHist[tid];
      sHist[tid] = 0;           // re-zero own bin for the next pass
      int x = vv;
      for (int off = 1; off < 64; off <<= 1) {
        int y = __shfl_up(x, off, 64);
        if (lane >= off) x += y;
      }
      if (lane == 63) sWaveSum[w] = x;
      __syncthreads();
      int add = 0;
      for (int ww = 0; ww < w; ++ww) add += sWaveSum[ww];
      x += add;
      int ex = x - vv;          // exclusive prefix over 256 bins
      if (ex <= want && want < ex + vv) {
        sPrefix = pref | ((unsigned)tid << shift);
        sWant   = want - ex;
      }
      __syncthreads();
    }
    if (tid == 0) {
      sSig[mm] = __uint_as_float(sPrefix) + 1e-5f;
      sPrefix = 0u; sWant = (NS * NS - 1) / 2;   // reset for second radix
    }
    __syncthreads();
  }

  float invK = -1.f / (2.f * sSig[0]);
  float invL = -1.f / (2.f * sSig[1]);

  // exp from registers into padded LDS
  {
    int i  = tid >> 3;          // row
    int j4 = (tid & 7) * 4;     // col base
    float fk[4] = { vK.x, vK.y, vK.z, vK.w };
    float fl[4] = { vL.x, vL.y, vL.z, vL.w };
    #pragma unroll
    for (int s = 0; s < 4; ++s) {
      sK[i * MPAD + j4 + s] = expf(fk[s] * invK);
      sL[i * MPAD + j4 + s] = expf(fl[s] * invL);
    }
  }
  __syncthreads();

  // row means (proven r,g shuffle pattern)
  {
    int r = tid >> 3, g = tid & 7;
    float pk = 0.f, pl = 0.f;
    #pragma unroll
    for (int s = 0; s < 4; ++s) {
      pk += sK[r * MPAD + g + 8 * s];
      pl += sL[r * MPAD + g + 8 * s];
    }
    for (int off = 4; off; off >>= 1) {
      pk += __shfl_down(pk, off, 8);
      pl += __shfl_down(pl, off, 8);
    }
    if (g == 0) { sRM[0][r] = pk * (1.f / 32.f); sRM[1][r] = pl * (1.f / 32.f); }
  }
  __syncthreads();

  // hsic = sum_ij (K_ij - rK_i)(L_ij - rL_j) / 961   (L symmetric)
  float part = 0.f;
  for (int q = tid; q < NS * NS; q += 256) {
    int i = q >> 5, j = q & 31;
    part += (sK[i * MPAD + j] - sRM[0][i]) * (sL[i * MPAD + j] - sRM[1][j]);
  }
  part = wave_reduce_add(part);
  if (lane == 0) sWaveRed[w] = part;
  __syncthreads();
  if (tid == 0)
    ws_hs[k] = (sWaveRed[0] + sWaveRed[1] + sWaveRed[2] + sWaveRed[3]) * (1.f / 961.f);
}

__global__ __launch_bounds__(256) void final_kernel(
    const float* __restrict__ ws_gate, const float* __restrict__ ws_hs,
    float* __restrict__ out) {
  __shared__ float sW[8];
  const int tid = threadIdx.x, lane = tid & 63, wave = tid >> 6;
  float g = 0.f;
  for (int i = tid; i < GATE_BLOCKS; i += 256) g += ws_gate[i];
  g = wave_reduce_add(g);
  if (lane == 0) sW[wave] = g;
  float h = (tid < K_INST) ? ws_hs[tid] : 0.f;
  h = wave_reduce_add(h);
  if (lane == 0) sW[4 + wave] = h;
  __syncthreads();
  if (tid == 0) {
    float gsum = sW[0] + sW[1] + sW[2] + sW[3];
    float hsum = sW[4] + sW[5] + sW[6] + sW[7];
    out[0] = hsum * (1.f / 256.f) + 1e-3f * (gsum / (65536.f * 512.f));
  }
}

extern "C" void kernel_launch(void* const* d_in, const int* in_sizes, int n_in,
                              void* d_out, int out_size, void* d_ws, size_t ws_size,
                              hipStream_t stream) {
  const float* dp   = (const float*)d_in[0];
  const float* gate = (const float*)d_in[1];
  const int*   inst = (const int*)d_in[2];
  const int*   bg   = (const int*)d_in[3];
  float* out = (float*)d_out;
  float* ws  = (float*)d_ws;
  float* ws_gate = ws;                    // [1024]
  float* ws_hs   = ws + 1024;             // [256]
  float* ws_dist = ws + 2048;             // [512*1024]

  fused_kernel<<<HSIC_BLOCKS + GATE_BLOCKS, 256, 0, stream>>>(
      dp, gate, inst, bg, ws_gate, ws_dist);
  contract_kernel<<<K_INST, 256, 0, stream>>>(ws_dist, ws_hs);
  final_kernel<<<1, 256, 0, stream>>>(ws_gate, ws_hs, out);
}

// Round 11
// 41.936 us; speedup vs baseline: 1.1583x; 1.1583x over previous
//
#include <hip/hip_runtime.h>
#include <hip/hip_bf16.h>

#define NS 32
#define FD 512
#define K_INST 256
#define MPAD 33              // 32x32 matrix padded to 33 cols
#define HSIC_BLOCKS 512      // one RBF matrix per block: k = bid>>1, m = bid&1
#define GATE_BLOCKS 1024
#define GATE_ITERS 32        // 8388608 float4 / (1024*256) exactly

__device__ __forceinline__ float wave_reduce_add(float v) {
  for (int off = 32; off; off >>= 1) v += __shfl_down(v, off, 64);
  return v;
}

__global__ __launch_bounds__(256) void fused_kernel(
    const float* __restrict__ dp, const float* __restrict__ gate,
    const int* __restrict__ inst_idx, const int* __restrict__ bg_idx,
    float* __restrict__ ws_gate, float* __restrict__ ws_mats,
    float* __restrict__ ws_means) {

  // 16 KB staging (32 rows x 32 float4 per chunk, XOR-swizzled), aliased
  // with the 4-wave partial-Gram buffer [4][1024] floats (disjoint lifetimes).
  __shared__ float4 sX4[NS * 32];        // 16384 B
  __shared__ float  sD[NS * MPAD];       // 4224 B (gram -> dist -> exp in place)
  __shared__ float  sRowM[NS];
  __shared__ float  sInv[NS];
  __shared__ int    sIdx[NS];
  __shared__ int    sHist[256];
  __shared__ int    sWaveSum[4];
  __shared__ float  sWaveRed[4];
  __shared__ unsigned sPrefix;
  __shared__ int    sWant;

  float* sPartF = reinterpret_cast<float*>(sX4);   // [4][1024] alias

  const int tid  = threadIdx.x;
  const int bid  = blockIdx.x;
  const int lane = tid & 63;
  const int w    = tid >> 6;

  if (bid >= HSIC_BLOCKS) {
    // ---- gate |x| partial sum: exactly 32 float4 per thread, no tail ----
    const int gb = bid - HSIC_BLOCKS;
    const float4* g4 = reinterpret_cast<const float4*>(gate);
    float s = 0.f;
    size_t base = (size_t)gb * 256 + tid;
    #pragma unroll 8
    for (int it = 0; it < GATE_ITERS; ++it) {
      float4 v = g4[base + (size_t)it * (GATE_BLOCKS * 256)];
      s += fabsf(v.x) + fabsf(v.y) + fabsf(v.z) + fabsf(v.w);
    }
    s = wave_reduce_add(s);
    if (lane == 0) sWaveRed[w] = s;
    __syncthreads();
    if (tid == 0) ws_gate[gb] = sWaveRed[0] + sWaveRed[1] + sWaveRed[2] + sWaveRed[3];
    return;
  }

  // ---- one RBF matrix: instance k, side m ----
  const int k  = bid >> 1;
  const int m  = bid & 1;
  const int li = lane >> 3;   // 0..7
  const int lj = lane & 7;    // 0..7
  const float4* dp4 = reinterpret_cast<const float4*>(dp);

  const int* idx = (m == 0 ? inst_idx : bg_idx) + k * NS;
  if (tid < NS) sIdx[tid] = idx[tid];
  __syncthreads();

  // 4x4 scalar accumulators: rows {li+8a}, cols {lj+8b}; K split across waves
  float acc[4][4];
  #pragma unroll
  for (int a = 0; a < 4; ++a)
    #pragma unroll
    for (int b = 0; b < 4; ++b) acc[a][b] = 0.f;

  // 4 chunks of 32 float4 (128 floats) per row. NO prefetch registers
  // (R5's pre[8] = +32 VGPR was the 128-cliff); ys streamed one at a time.
  #pragma unroll 1
  for (int ch = 0; ch < 4; ++ch) {
    #pragma unroll
    for (int kk = 0; kk < 4; ++kk) {
      int q = tid + 256 * kk;
      int r = q >> 5, c = q & 31;
      sX4[r * 32 + (c ^ (r & 7))] = dp4[(size_t)sIdx[r] * 128 + ch * 32 + c];
    }
    __syncthreads();
    // wave w covers logical f4-cols [8w, 8w+8) of this chunk
    #pragma unroll 2
    for (int c = 0; c < 8; ++c) {
      int cl = 8 * w + c;
      float4 xs[4];
      #pragma unroll
      for (int s = 0; s < 4; ++s)
        xs[s] = sX4[(li + 8 * s) * 32 + (cl ^ li)];   // 8-way broadcast, conflict-free
      #pragma unroll
      for (int b = 0; b < 4; ++b) {
        float4 y = sX4[(lj + 8 * b) * 32 + (cl ^ lj)];
        #pragma unroll
        for (int a = 0; a < 4; ++a)
          acc[a][b] += xs[a].x * y.x + xs[a].y * y.y
                     + xs[a].z * y.z + xs[a].w * y.w;
      }
    }
    __syncthreads();
  }

  // per-wave partials into aliased buffer, bank-swizzled slots (2-way free)
  #pragma unroll
  for (int a = 0; a < 4; ++a)
    #pragma unroll
    for (int b = 0; b < 4; ++b) {
      int A = li + 8 * a, B = lj + 8 * b;
      sPartF[w * 1024 + A * 32 + (B ^ ((A & 3) << 3))] = acc[a][b];
    }
  __syncthreads();
  // cross-wave reduce, de-swizzle -> padded Gram in sD
  for (int p = tid; p < 1024; p += 256) {
    float s = sPartF[p] + sPartF[1024 + p] + sPartF[2048 + p] + sPartF[3072 + p];
    int A = p >> 5, Bs = p & 31;
    int B = Bs ^ ((A & 3) << 3);
    sD[A * MPAD + B] = s;
  }
  __syncthreads();
  if (tid < NS) sInv[tid] = 1.f / fmaxf(sqrtf(sD[tid * MPAD + tid]), 1e-12f);
  __syncthreads();
  // dist = max(2 - 2*Gn, 0), exact 0 diagonal, in place
  for (int p = tid; p < 1024; p += 256) {
    int i = p >> 5, j = p & 31;
    float g = sD[i * MPAD + j];
    sD[i * MPAD + j] = (i == j) ? 0.f : fmaxf(2.f - 2.f * g * sInv[i] * sInv[j], 0.f);
  }
  if (tid == 0) { sPrefix = 0u; sWant = (NS * NS - 1) / 2; }  // 511th smallest
  __syncthreads();

  // exact lower-median via 4-pass MSD radix select on f32 bit patterns (all >= 0)
  // (verbatim R4: plain atomics proved faster than ballot-dedup, R9)
  for (int shift = 24; shift >= 0; shift -= 8) {
    sHist[tid] = 0;
    __syncthreads();
    unsigned pref = sPrefix;
    int want = sWant;
    unsigned hi_mask = (shift == 24) ? 0u : (0xFFFFFFFFu << (shift + 8));
    for (int q = tid; q < NS * NS; q += 256) {
      unsigned u = __float_as_uint(sD[(q >> 5) * MPAD + (q & 31)]);
      if ((u & hi_mask) == pref) atomicAdd(&sHist[(u >> shift) & 255], 1);
    }
    __syncthreads();
    int v = sHist[tid];
    int x = v;
    for (int off = 1; off < 64; off <<= 1) {
      int y = __shfl_up(x, off, 64);
      if (lane >= off) x += y;
    }
    if (lane == 63) sWaveSum[w] = x;
    __syncthreads();
    int add = 0;
    for (int ww = 0; ww < w; ++ww) add += sWaveSum[ww];
    x += add;
    int ex = x - v;            // exclusive prefix over 256 bins
    if (ex <= want && want < ex + v) {
      sPrefix = pref | ((unsigned)tid << shift);
      sWant   = want - ex;
    }
    __syncthreads();
  }
  float sigma2 = __uint_as_float(sPrefix) + 1e-5f;

  // exp in place
  float inv2s = -1.f / (2.f * sigma2);
  for (int q = tid; q < NS * NS; q += 256) {
    int i = q >> 5, j = q & 31;
    sD[i * MPAD + j] = expf(sD[i * MPAD + j] * inv2s);
  }
  __syncthreads();

  // row means
  {
    int r = tid >> 3, g = tid & 7;
    float p = 0.f;
    #pragma unroll
    for (int s = 0; s < 4; ++s) p += sD[r * MPAD + g + 8 * s];
    for (int off = 4; off; off >>= 1) p += __shfl_down(p, off, 8);
    if (g == 0) sRowM[r] = p * (1.f / 32.f);
  }
  __syncthreads();

  // write matrix (compact [1024]) + row means to workspace
  float* mat = ws_mats + (size_t)bid * 1024;
  for (int q = tid; q < NS * NS; q += 256)
    mat[q] = sD[(q >> 5) * MPAD + (q & 31)];
  if (tid < NS) ws_means[bid * NS + tid] = sRowM[tid];
}

__global__ __launch_bounds__(256) void contract_kernel(
    const float* __restrict__ ws_mats, const float* __restrict__ ws_means,
    float* __restrict__ ws_hs) {
  __shared__ float sRM[2][NS];
  __shared__ float sWaveRed[4];
  const int k = blockIdx.x;
  const int tid = threadIdx.x, lane = tid & 63, w = tid >> 6;
  const float* Km = ws_mats + (size_t)(k * 2 + 0) * 1024;
  const float* Lm = ws_mats + (size_t)(k * 2 + 1) * 1024;
  if (tid < 64) sRM[tid >> 5][tid & 31] = ws_means[(k * 2 + (tid >> 5)) * NS + (tid & 31)];
  __syncthreads();
  float part = 0.f;
  for (int q = tid; q < NS * NS; q += 256) {
    int i = q >> 5, j = q & 31;
    part += (Km[q] - sRM[0][i]) * (Lm[q] - sRM[1][j]);  // L symmetric: L_ji == L_ij
  }
  part = wave_reduce_add(part);
  if (lane == 0) sWaveRed[w] = part;
  __syncthreads();
  if (tid == 0)
    ws_hs[k] = (sWaveRed[0] + sWaveRed[1] + sWaveRed[2] + sWaveRed[3]) * (1.f / 961.f);
}

__global__ __launch_bounds__(256) void final_kernel(
    const float* __restrict__ ws_gate, const float* __restrict__ ws_hs,
    float* __restrict__ out) {
  __shared__ float sW[8];
  const int tid = threadIdx.x, lane = tid & 63, wave = tid >> 6;
  float g = 0.f;
  for (int i = tid; i < GATE_BLOCKS; i += 256) g += ws_gate[i];
  g = wave_reduce_add(g);
  if (lane == 0) sW[wave] = g;
  float h = (tid < K_INST) ? ws_hs[tid] : 0.f;
  h = wave_reduce_add(h);
  if (lane == 0) sW[4 + wave] = h;
  __syncthreads();
  if (tid == 0) {
    float gsum = sW[0] + sW[1] + sW[2] + sW[3];
    float hsum = sW[4] + sW[5] + sW[6] + sW[7];
    out[0] = hsum * (1.f / 256.f) + 1e-3f * (gsum / (65536.f * 512.f));
  }
}

extern "C" void kernel_launch(void* const* d_in, const int* in_sizes, int n_in,
                              void* d_out, int out_size, void* d_ws, size_t ws_size,
                              hipStream_t stream) {
  const float* dp   = (const float*)d_in[0];
  const float* gate = (const float*)d_in[1];
  const int*   inst = (const int*)d_in[2];
  const int*   bg   = (const int*)d_in[3];
  float* out = (float*)d_out;
  float* ws  = (float*)d_ws;
  float* ws_gate  = ws;                          // [1024]
  float* ws_hs    = ws + 1024;                   // [256]
  float* ws_means = ws + 1024 + 256;             // [512*32]
  float* ws_mats  = ws + 1024 + 256 + 512 * 32;  // [512*1024]

  fused_kernel<<<HSIC_BLOCKS + GATE_BLOCKS, 256, 0, stream>>>(
      dp, gate, inst, bg, ws_gate, ws_mats, ws_means);
  contract_kernel<<<K_INST, 256, 0, stream>>>(ws_mats, ws_means, ws_hs);
  final_kernel<<<1, 256, 0, stream>>>(ws_gate, ws_hs, out);
}

// Round 12
// 40.538 us; speedup vs baseline: 1.1982x; 1.0345x over previous
//
#include <hip/hip_runtime.h>
#include <hip/hip_bf16.h>

#define NS 32
#define FD 512
#define K_INST 256
#define MPAD 33              // 32x32 matrix padded to 33 cols
#define HSIC_BLOCKS 512      // one RBF matrix per block: k = bid>>1, m = bid&1
#define GATE_BLOCKS 1024
#define GATE_ITERS 32        // 8388608 float4 / (1024*256) exactly
// Dynamic LDS pad: 22.5KB static + 16KB dynamic = 38.9KB -> 4 blocks/CU,
// matching R4's proven residency/stagger while keeping R11's cheaper Gram.
#define LDS_PAD_BYTES 16384

__device__ __forceinline__ float wave_reduce_add(float v) {
  for (int off = 32; off; off >>= 1) v += __shfl_down(v, off, 64);
  return v;
}

__global__ __launch_bounds__(256) void fused_kernel(
    const float* __restrict__ dp, const float* __restrict__ gate,
    const int* __restrict__ inst_idx, const int* __restrict__ bg_idx,
    float* __restrict__ ws_gate, float* __restrict__ ws_mats,
    float* __restrict__ ws_means) {

  // 16 KB staging (32 rows x 32 float4 per chunk, XOR-swizzled), aliased
  // with the 4-wave partial-Gram buffer [4][1024] floats (disjoint lifetimes).
  __shared__ float4 sX4[NS * 32];        // 16384 B
  __shared__ float  sD[NS * MPAD];       // 4224 B (gram -> dist -> exp in place)
  __shared__ float  sRowM[NS];
  __shared__ float  sInv[NS];
  __shared__ int    sIdx[NS];
  __shared__ int    sHist[256];
  __shared__ int    sWaveSum[4];
  __shared__ float  sWaveRed[4];
  __shared__ unsigned sPrefix;
  __shared__ int    sWant;
  extern __shared__ float sPad[];        // 16 KB dynamic pad (occupancy shaping)

  float* sPartF = reinterpret_cast<float*>(sX4);   // [4][1024] alias

  const int tid  = threadIdx.x;
  const int bid  = blockIdx.x;
  const int lane = tid & 63;
  const int w    = tid >> 6;

  if (bid >= HSIC_BLOCKS) {
    // ---- gate |x| partial sum: exactly 32 float4 per thread, no tail ----
    const int gb = bid - HSIC_BLOCKS;
    const float4* g4 = reinterpret_cast<const float4*>(gate);
    float s = 0.f;
    size_t base = (size_t)gb * 256 + tid;
    #pragma unroll 8
    for (int it = 0; it < GATE_ITERS; ++it) {
      float4 v = g4[base + (size_t)it * (GATE_BLOCKS * 256)];
      s += fabsf(v.x) + fabsf(v.y) + fabsf(v.z) + fabsf(v.w);
    }
    s = wave_reduce_add(s);
    if (lane == 0) sWaveRed[w] = s;
    __syncthreads();
    if (tid == 0) ws_gate[gb] = sWaveRed[0] + sWaveRed[1] + sWaveRed[2] + sWaveRed[3];
    return;
  }

  // ---- one RBF matrix: instance k, side m ----
  const int k  = bid >> 1;
  const int m  = bid & 1;
  const int li = lane >> 3;   // 0..7
  const int lj = lane & 7;    // 0..7
  const float4* dp4 = reinterpret_cast<const float4*>(dp);

  const int* idx = (m == 0 ? inst_idx : bg_idx) + k * NS;
  if (tid < NS) sIdx[tid] = idx[tid];
  __syncthreads();

  // 4x4 scalar accumulators: rows {li+8a}, cols {lj+8b}; K split across waves
  float acc[4][4];
  #pragma unroll
  for (int a = 0; a < 4; ++a)
    #pragma unroll
    for (int b = 0; b < 4; ++b) acc[a][b] = 0.f;

  // 4 chunks of 32 float4 (128 floats) per row. NO prefetch registers
  // (R5's pre[8] = +32 VGPR was the 128-cliff); ys streamed one at a time.
  #pragma unroll 1
  for (int ch = 0; ch < 4; ++ch) {
    #pragma unroll
    for (int kk = 0; kk < 4; ++kk) {
      int q = tid + 256 * kk;
      int r = q >> 5, c = q & 31;
      sX4[r * 32 + (c ^ (r & 7))] = dp4[(size_t)sIdx[r] * 128 + ch * 32 + c];
    }
    __syncthreads();
    // wave w covers logical f4-cols [8w, 8w+8) of this chunk
    #pragma unroll 2
    for (int c = 0; c < 8; ++c) {
      int cl = 8 * w + c;
      float4 xs[4];
      #pragma unroll
      for (int s = 0; s < 4; ++s)
        xs[s] = sX4[(li + 8 * s) * 32 + (cl ^ li)];   // 8-way broadcast, conflict-free
      #pragma unroll
      for (int b = 0; b < 4; ++b) {
        float4 y = sX4[(lj + 8 * b) * 32 + (cl ^ lj)];
        #pragma unroll
        for (int a = 0; a < 4; ++a)
          acc[a][b] += xs[a].x * y.x + xs[a].y * y.y
                     + xs[a].z * y.z + xs[a].w * y.w;
      }
    }
    __syncthreads();
  }

  // per-wave partials into aliased buffer, bank-swizzled slots (2-way free)
  #pragma unroll
  for (int a = 0; a < 4; ++a)
    #pragma unroll
    for (int b = 0; b < 4; ++b) {
      int A = li + 8 * a, B = lj + 8 * b;
      sPartF[w * 1024 + A * 32 + (B ^ ((A & 3) << 3))] = acc[a][b];
    }
  __syncthreads();
  // cross-wave reduce, de-swizzle -> padded Gram in sD
  for (int p = tid; p < 1024; p += 256) {
    float s = sPartF[p] + sPartF[1024 + p] + sPartF[2048 + p] + sPartF[3072 + p];
    int A = p >> 5, Bs = p & 31;
    int B = Bs ^ ((A & 3) << 3);
    sD[A * MPAD + B] = s;
  }
  __syncthreads();
  if (tid < NS) sInv[tid] = 1.f / fmaxf(sqrtf(sD[tid * MPAD + tid]), 1e-12f);
  __syncthreads();
  // dist = max(2 - 2*Gn, 0), exact 0 diagonal, in place
  for (int p = tid; p < 1024; p += 256) {
    int i = p >> 5, j = p & 31;
    float g = sD[i * MPAD + j];
    sD[i * MPAD + j] = (i == j) ? 0.f : fmaxf(2.f - 2.f * g * sInv[i] * sInv[j], 0.f);
  }
  if (tid == 0) { sPrefix = 0u; sWant = (NS * NS - 1) / 2; }  // 511th smallest
  __syncthreads();

  // exact lower-median via 4-pass MSD radix select on f32 bit patterns (all >= 0)
  for (int shift = 24; shift >= 0; shift -= 8) {
    sHist[tid] = 0;
    __syncthreads();
    unsigned pref = sPrefix;
    int want = sWant;
    unsigned hi_mask = (shift == 24) ? 0u : (0xFFFFFFFFu << (shift + 8));
    for (int q = tid; q < NS * NS; q += 256) {
      unsigned u = __float_as_uint(sD[(q >> 5) * MPAD + (q & 31)]);
      if ((u & hi_mask) == pref) atomicAdd(&sHist[(u >> shift) & 255], 1);
    }
    __syncthreads();
    int v = sHist[tid];
    int x = v;
    for (int off = 1; off < 64; off <<= 1) {
      int y = __shfl_up(x, off, 64);
      if (lane >= off) x += y;
    }
    if (lane == 63) sWaveSum[w] = x;
    __syncthreads();
    int add = 0;
    for (int ww = 0; ww < w; ++ww) add += sWaveSum[ww];
    x += add;
    int ex = x - v;            // exclusive prefix over 256 bins
    if (ex <= want && want < ex + v) {
      sPrefix = pref | ((unsigned)tid << shift);
      sWant   = want - ex;
    }
    __syncthreads();
  }
  float sigma2 = __uint_as_float(sPrefix) + 1e-5f;

  // exp in place
  float inv2s = -1.f / (2.f * sigma2);
  for (int q = tid; q < NS * NS; q += 256) {
    int i = q >> 5, j = q & 31;
    sD[i * MPAD + j] = expf(sD[i * MPAD + j] * inv2s);
  }
  __syncthreads();

  // row means
  {
    int r = tid >> 3, g = tid & 7;
    float p = 0.f;
    #pragma unroll
    for (int s = 0; s < 4; ++s) p += sD[r * MPAD + g + 8 * s];
    for (int off = 4; off; off >>= 1) p += __shfl_down(p, off, 8);
    if (g == 0) sRowM[r] = p * (1.f / 32.f);
  }
  __syncthreads();

  // write matrix (compact [1024]) + row means to workspace
  float* mat = ws_mats + (size_t)bid * 1024;
  for (int q = tid; q < NS * NS; q += 256)
    mat[q] = sD[(q >> 5) * MPAD + (q & 31)];
  if (tid < NS) ws_means[bid * NS + tid] = sRowM[tid];
}

__global__ __launch_bounds__(256) void contract_kernel(
    const float* __restrict__ ws_mats, const float* __restrict__ ws_means,
    float* __restrict__ ws_hs) {
  __shared__ float sRM[2][NS];
  __shared__ float sWaveRed[4];
  const int k = blockIdx.x;
  const int tid = threadIdx.x, lane = tid & 63, w = tid >> 6;
  const float* Km = ws_mats + (size_t)(k * 2 + 0) * 1024;
  const float* Lm = ws_mats + (size_t)(k * 2 + 1) * 1024;
  if (tid < 64) sRM[tid >> 5][tid & 31] = ws_means[(k * 2 + (tid >> 5)) * NS + (tid & 31)];
  __syncthreads();
  float part = 0.f;
  for (int q = tid; q < NS * NS; q += 256) {
    int i = q >> 5, j = q & 31;
    part += (Km[q] - sRM[0][i]) * (Lm[q] - sRM[1][j]);  // L symmetric: L_ji == L_ij
  }
  part = wave_reduce_add(part);
  if (lane == 0) sWaveRed[w] = part;
  __syncthreads();
  if (tid == 0)
    ws_hs[k] = (sWaveRed[0] + sWaveRed[1] + sWaveRed[2] + sWaveRed[3]) * (1.f / 961.f);
}

__global__ __launch_bounds__(256) void final_kernel(
    const float* __restrict__ ws_gate, const float* __restrict__ ws_hs,
    float* __restrict__ out) {
  __shared__ float sW[8];
  const int tid = threadIdx.x, lane = tid & 63, wave = tid >> 6;
  float g = 0.f;
  for (int i = tid; i < GATE_BLOCKS; i += 256) g += ws_gate[i];
  g = wave_reduce_add(g);
  if (lane == 0) sW[wave] = g;
  float h = (tid < K_INST) ? ws_hs[tid] : 0.f;
  h = wave_reduce_add(h);
  if (lane == 0) sW[4 + wave] = h;
  __syncthreads();
  if (tid == 0) {
    float gsum = sW[0] + sW[1] + sW[2] + sW[3];
    float hsum = sW[4] + sW[5] + sW[6] + sW[7];
    out[0] = hsum * (1.f / 256.f) + 1e-3f * (gsum / (65536.f * 512.f));
  }
}

extern "C" void kernel_launch(void* const* d_in, const int* in_sizes, int n_in,
                              void* d_out, int out_size, void* d_ws, size_t ws_size,
                              hipStream_t stream) {
  const float* dp   = (const float*)d_in[0];
  const float* gate = (const float*)d_in[1];
  const int*   inst = (const int*)d_in[2];
  const int*   bg   = (const int*)d_in[3];
  float* out = (float*)d_out;
  float* ws  = (float*)d_ws;
  float* ws_gate  = ws;                          // [1024]
  float* ws_hs    = ws + 1024;                   // [256]
  float* ws_means = ws + 1024 + 256;             // [512*32]
  float* ws_mats  = ws + 1024 + 256 + 512 * 32;  // [512*1024]

  fused_kernel<<<HSIC_BLOCKS + GATE_BLOCKS, 256, LDS_PAD_BYTES, stream>>>(
      dp, gate, inst, bg, ws_gate, ws_mats, ws_means);
  contract_kernel<<<K_INST, 256, 0, stream>>>(ws_mats, ws_means, ws_hs);
  final_kernel<<<1, 256, 0, stream>>>(ws_gate, ws_hs, out);
}